// Round 3
// baseline (240.295 us; speedup 1.0000x reference)
//
#include <hip/hip_runtime.h>

#define NN 207
#define NE 1722
#define NS 288
#define LDIM 64
#define KSTEPS 7          // K padded to 224 (7 x 32)
#define RT_TILES 13       // rows padded to 208 (13 x 16)
#define XT_RS 232         // xT LDS row stride in bf16 elems (464 B, 16B-aligned)

typedef short bf16x8 __attribute__((ext_vector_type(8)));
typedef float f32x4  __attribute__((ext_vector_type(4)));

// f32 -> bf16 (round-to-nearest-even-ish), result in low 16 bits
__device__ __forceinline__ unsigned int f2bf(float f) {
    unsigned int u = __float_as_uint(f);
    return (u + 0x7FFFu + ((u >> 16) & 1u)) >> 16;
}

// ===========================================================================
// FAST PATH
// ===========================================================================

// ---------------------------------------------------------------------------
// P1: build M_s = (1+wsl+deg)*I - A_s per slot, bf16, pre-swizzled into MFMA
// 16x16x32 A-fragment order. Grid = 288 slots x 4 row-passes (64 rows each).
// Fragment (s, rt, ks) = 1 KB: lane l holds A[m=l&15][k=ks*32+(l>>4)*8+j],
// packed as 4 dwords (2 bf16 each) at dword index (l*4 + j/2).
// ---------------------------------------------------------------------------
__global__ __launch_bounds__(256) void build_m_kernel(
    const float* __restrict__ wd,   // (288, 1722)
    const float* __restrict__ wsl,  // (288, 207)
    const int* __restrict__ ei, const int* __restrict__ ej,
    unsigned int* __restrict__ fragbuf) {
    __shared__ float M[64 * 224];   // 57344 B
    __shared__ float deg[NN];
    const int sb = blockIdx.x;
    const int s = sb >> 2, p = sb & 3;
    const int r0 = p * 64;
    const int t = threadIdx.x;

    for (int i = t; i < 64 * 224; i += 256) M[i] = 0.f;
    for (int n = t; n < NN; n += 256) deg[n] = 0.f;
    __syncthreads();

    const float* wrow = wd + (size_t)s * NE;
    for (int e = t; e < NE; e += 256) {
        const float w = wrow[e];
        const int i = ei[e], j = ej[e];
        atomicAdd(&deg[i], w);
        atomicAdd(&deg[j], w);
        const int ri = i - r0;
        if (ri >= 0 && ri < 64) atomicAdd(&M[ri * 224 + j], -w);
        const int rj = j - r0;
        if (rj >= 0 && rj < 64) atomicAdd(&M[rj * 224 + i], -w);
    }
    __syncthreads();
    // diagonal: M[n][n] += 1 + wsl + deg[n]
    if (t < 64) {
        const int n = r0 + t;
        if (n < NN) M[t * 224 + n] += 1.f + wsl[(size_t)s * NN + n] + deg[n];
    }
    __syncthreads();

    const int ntiles = (p < 3) ? 4 : 1;   // p=3 covers rows 192..207 only
    for (int it = 0; it < ntiles * KSTEPS; ++it) {
        const int rtl = it / KSTEPS, ks = it % KSTEPS;
        const int rt = p * 4 + rtl;
        const int lane = t >> 2, pr = t & 3;
        const int row = rtl * 16 + (lane & 15);
        const int k = ks * 32 + (lane >> 4) * 8 + pr * 2;
        const unsigned int v = f2bf(M[row * 224 + k]) |
                               (f2bf(M[row * 224 + k + 1]) << 16);
        fragbuf[(((size_t)s * RT_TILES + rt) * KSTEPS + ks) * 256 + t] = v;
    }
}

// ---------------------------------------------------------------------------
// P2: one block per batch. out[b] = M_{ind[b]} @ x[b] + bias.
// Stage x transposed->bf16 in LDS; each wave owns a 16-wide L column tile,
// holds its 7 B-frags in regs; streams A-frags from global (double-buffered).
// ---------------------------------------------------------------------------
__global__ __launch_bounds__(256, 4) void gemm_kernel(
    const float* __restrict__ inputs,   // (B, 2, 207, 64)
    const float* __restrict__ bias_d,   // (288, 207)
    const int*   __restrict__ ind,      // (B,)
    const unsigned int* __restrict__ fragbuf,
    float* __restrict__ out) {          // (B, 207, 64)
    __shared__ __align__(16) unsigned short xT[LDIM * XT_RS];  // 29696 B

    const int b = blockIdx.x, t = threadIdx.x;
    const int s = ind[b];
    const float* xb = inputs + (size_t)b * (2 * NN * LDIM);    // channel 0

    // Stage x[k][n] -> xT[n][k] bf16, zero-pad k in [207,224)
    for (int it = t; it < 112 * 64; it += 256) {
        const int n = it & 63, kp = it >> 6;
        unsigned int v = 0;
        if (kp < 103) {
            v = f2bf(xb[(2 * kp) * 64 + n]) | (f2bf(xb[(2 * kp + 1) * 64 + n]) << 16);
        } else if (kp == 103) {
            v = f2bf(xb[206 * 64 + n]);   // k=207 pad -> 0 in high half
        }
        *(unsigned int*)&xT[n * XT_RS + kp * 2] = v;
    }
    __syncthreads();

    const int lane = t & 63, wv = t >> 6;
    const int quad = lane >> 4, m16 = lane & 15;

    // B fragments for this wave's column tile (held in regs, reused x13)
    bf16x8 Bf[KSTEPS];
    #pragma unroll
    for (int ks = 0; ks < KSTEPS; ++ks)
        Bf[ks] = *(const bf16x8*)&xT[(wv * 16 + m16) * XT_RS + ks * 32 + quad * 8];

    const bf16x8* Ab = ((const bf16x8*)fragbuf) +
                       (size_t)s * RT_TILES * KSTEPS * 64 + lane;
    float* ob = out + (size_t)b * NN * LDIM + wv * 16 + m16;
    const float* bias_row = bias_d + (size_t)s * NN;

    bf16x8 A0[KSTEPS], A1[KSTEPS];
    #pragma unroll
    for (int ks = 0; ks < KSTEPS; ++ks) A0[ks] = Ab[ks * 64];

    #pragma unroll
    for (int rt = 0; rt < RT_TILES; ++rt) {
        const bf16x8* Acur = (rt & 1) ? A1 : A0;
        bf16x8*       Anxt = (rt & 1) ? A0 : A1;
        if (rt + 1 < RT_TILES) {
            const bf16x8* An = Ab + (size_t)(rt + 1) * KSTEPS * 64;
            #pragma unroll
            for (int ks = 0; ks < KSTEPS; ++ks) Anxt[ks] = An[ks * 64];
        }
        f32x4 acc = {0.f, 0.f, 0.f, 0.f};
        #pragma unroll
        for (int ks = 0; ks < KSTEPS; ++ks)
            acc = __builtin_amdgcn_mfma_f32_16x16x32_bf16(Acur[ks], Bf[ks], acc, 0, 0, 0);
        #pragma unroll
        for (int r = 0; r < 4; ++r) {
            const int node = rt * 16 + quad * 4 + r;
            if (node < NN) ob[(size_t)node * 64] = acc[r] + bias_row[node];
        }
    }
}

// ===========================================================================
// FALLBACK PATH (R2, proven) — used if ws_size is too small for fragbuf
// ===========================================================================
__device__ __forceinline__ unsigned int f2bf_hi(float f) {
    unsigned int u = __float_as_uint(f);
    return (u + 0x7FFFu + ((u >> 16) & 1u)) & 0xFFFF0000u;
}

__global__ __launch_bounds__(256) void build_csr_kernel(
    const int* __restrict__ edge_i, const int* __restrict__ edge_j,
    int* __restrict__ row_start, unsigned int* __restrict__ csr_packed) {
    __shared__ int cnt[NN];
    __shared__ int rs[NN + 1];
    const int tid = threadIdx.x;
    for (int n = tid; n < NN; n += 256) cnt[n] = 0;
    __syncthreads();
    for (int e = tid; e < NE; e += 256) {
        atomicAdd(&cnt[edge_i[e]], 1);
        atomicAdd(&cnt[edge_j[e]], 1);
    }
    __syncthreads();
    if (tid == 0) {
        int acc = 0;
        for (int n = 0; n < NN; ++n) { rs[n] = acc; acc += cnt[n]; }
        rs[NN] = acc;
    }
    __syncthreads();
    for (int n = tid; n <= NN; n += 256) row_start[n] = rs[n];
    for (int n = tid; n < NN; n += 256) cnt[n] = rs[n];
    __syncthreads();
    for (int e = tid; e < NE; e += 256) {
        const unsigned int i = edge_i[e], j = edge_j[e];
        const unsigned int ep = ((unsigned int)e) << 8;
        int p = atomicAdd(&cnt[i], 1);
        csr_packed[p] = ep | j;
        int q = atomicAdd(&cnt[j], 1);
        csr_packed[q] = ep | i;
    }
}

__global__ __launch_bounds__(256) void coef_kernel(
    const float* __restrict__ weight_diff, const float* __restrict__ bias_diffusion,
    const float* __restrict__ weight_self_loop,
    const int* __restrict__ row_start, const unsigned int* __restrict__ csr_packed,
    float2* __restrict__ coefbias) {
    __shared__ float wrow[NE];
    const int s = blockIdx.x;
    for (int e = threadIdx.x; e < NE; e += 256)
        wrow[e] = weight_diff[(size_t)s * NE + e];
    __syncthreads();
    const int n = threadIdx.x;
    if (n < NN) {
        float d = 0.f;
        const int e0 = row_start[n], e1 = row_start[n + 1];
        for (int k = e0; k < e1; ++k) d += wrow[csr_packed[k] >> 8];
        coefbias[s * NN + n] = make_float2(
            1.f + weight_self_loop[s * NN + n] + d, bias_diffusion[s * NN + n]);
    }
}

__global__ __launch_bounds__(512, 8) void diffusion_gcn_kernel(
    const float* __restrict__ inputs, const float* __restrict__ weight_diff,
    const int* __restrict__ ind, const int* __restrict__ row_start,
    const unsigned int* __restrict__ csr_packed,
    const float2* __restrict__ coefbias, float* __restrict__ out) {
    __shared__ unsigned short xs[NN * LDIM];
    __shared__ unsigned int   wnb[2 * NE];
    __shared__ unsigned short rs[NN + 1];
    const int b = blockIdx.x, tid = threadIdx.x;
    const int slot = ind[b];
    const float* xb = inputs + (size_t)b * (2 * NN * LDIM);
    const float4* xb4 = (const float4*)xb;
    for (int k = tid; k < (NN * LDIM) / 4; k += 512) {
        const float4 v = xb4[k];
        const unsigned int lo = (f2bf_hi(v.x) >> 16) | f2bf_hi(v.y);
        const unsigned int hi = (f2bf_hi(v.z) >> 16) | f2bf_hi(v.w);
        ((uint2*)xs)[k] = make_uint2(lo, hi);
    }
    const float* wrow = weight_diff + (size_t)slot * NE;
    for (int k = tid; k < 2 * NE; k += 512) {
        const unsigned int c = csr_packed[k];
        wnb[k] = f2bf_hi(wrow[c >> 8]) | (c & 255u);
    }
    for (int n = tid; n <= NN; n += 512) rs[n] = (unsigned short)row_start[n];
    __syncthreads();
    const int lane = tid & 63, wv = tid >> 6;
    float* ob = out + (size_t)b * (NN * LDIM);
    for (int n = wv; n < NN; n += 8) {
        const int e0 = rs[n], e1 = rs[n + 1];
        float s = 0.f;
        #pragma unroll 4
        for (int k = e0; k < e1; ++k) {
            const unsigned int p = wnb[k];
            const float w = __uint_as_float(p & 0xFFFF0000u);
            const float xv = __uint_as_float((unsigned int)xs[(p & 255u) * LDIM + lane] << 16);
            s = fmaf(w, xv, s);
        }
        const float2 cb = coefbias[slot * NN + n];
        const float xg = xb[n * LDIM + lane];
        ob[n * LDIM + lane] = fmaf(cb.x, xg, cb.y) - s;
    }
}

// ===========================================================================
extern "C" void kernel_launch(void* const* d_in, const int* in_sizes, int n_in,
                              void* d_out, int out_size, void* d_ws, size_t ws_size,
                              hipStream_t stream) {
    const float* inputs           = (const float*)d_in[0];
    const float* weight_diff      = (const float*)d_in[1];
    const float* bias_diffusion   = (const float*)d_in[2];
    const float* weight_self_loop = (const float*)d_in[3];
    const int*   ind              = (const int*)d_in[4];
    const int*   edge_i           = (const int*)d_in[5];
    const int*   edge_j           = (const int*)d_in[6];
    float* out = (float*)d_out;
    const int B = in_sizes[4];

    const size_t FRAG_BYTES = (size_t)NS * RT_TILES * KSTEPS * 1024;  // 26,836,992

    if (ws_size >= FRAG_BYTES) {
        unsigned int* fragbuf = (unsigned int*)d_ws;
        build_m_kernel<<<NS * 4, 256, 0, stream>>>(
            weight_diff, weight_self_loop, edge_i, edge_j, fragbuf);
        gemm_kernel<<<B, 256, 0, stream>>>(
            inputs, bias_diffusion, ind, fragbuf, out);
    } else {
        int*          row_start  = (int*)d_ws;
        unsigned int* csr_packed = (unsigned int*)((char*)d_ws + 832);
        float2*       coefbias   = (float2*)((char*)d_ws + 14608);
        build_csr_kernel<<<1, 256, 0, stream>>>(edge_i, edge_j, row_start, csr_packed);
        coef_kernel<<<NS, 256, 0, stream>>>(
            weight_diff, bias_diffusion, weight_self_loop, row_start, csr_packed, coefbias);
        diffusion_gcn_kernel<<<B, 512, 0, stream>>>(
            inputs, weight_diff, ind, row_start, csr_packed, coefbias, out);
    }
}